// Round 1
// baseline (510.114 us; speedup 1.0000x reference)
//
#include <hip/hip_runtime.h>
#include <stdint.h>

typedef float f32x4 __attribute__((ext_vector_type(4)));
typedef short s16x8 __attribute__((ext_vector_type(8)));
typedef unsigned short u16;

#define DEVI static __device__ __forceinline__

DEVI u16 f2bf(float f){
  unsigned u = __builtin_bit_cast(unsigned, f);
  u += 0x7fffu + ((u >> 16) & 1u);
  return (u16)(u >> 16);
}
DEVI float bf2f(u16 h){ return __builtin_bit_cast(float, ((unsigned)h) << 16); }

static constexpr unsigned RANK = 120795954u;   // floor(0.9 * (2*16*2048*2048 - 1))
static constexpr float QFRAC = 0.3f;           // fractional part of 0.9*(n-1)
static constexpr float CW = 1.0f / 512.0f;     // coarse bin width, range [0,16)

// ---------------- split f32 -> bf16 hi + bf16 lo ----------------
__global__ __launch_bounds__(256) void split_k(const float* __restrict__ src,
    u16* __restrict__ hi, u16* __restrict__ lo, int n4){
  int stride = gridDim.x * 256;
  for (int i = blockIdx.x * 256 + threadIdx.x; i < n4; i += stride){
    float4 v = ((const float4*)src)[i];
    u16 h0 = f2bf(v.x), h1 = f2bf(v.y), h2 = f2bf(v.z), h3 = f2bf(v.w);
    ushort4 hv = make_ushort4(h0, h1, h2, h3);
    ushort4 lv = make_ushort4(f2bf(v.x - bf2f(h0)), f2bf(v.y - bf2f(h1)),
                              f2bf(v.z - bf2f(h2)), f2bf(v.w - bf2f(h3)));
    ((ushort4*)hi)[i] = hv;
    ((ushort4*)lo)[i] = lv;
  }
}

// ---------------- split-bf16 GEMM: C = A * B^T, A[M,K], B[N,K] both K-contig ----
// OMODE 0: write hi/lo bf16 to [B,H,S,D] head layout (Q,K)
// OMODE 1: write hi bf16 to [B,H,D,S] transposed head layout (V^T)
// OMODE 2: write f32 to [M,1024] (final output)
template<int OMODE>
__global__ __launch_bounds__(256) void gemm_bt(
    const u16* __restrict__ Ahi, const u16* __restrict__ Alo,
    const u16* __restrict__ Bhi, const u16* __restrict__ Blo,
    void* __restrict__ out0, void* __restrict__ out1, int K)
{
  __shared__ u16 lA[2][128][40];   // [hi/lo][row][k], pad 40 => 80B row stride
  __shared__ u16 lB[2][64][40];
  const int tid = threadIdx.x;
  const int m0 = blockIdx.y * 128, n0 = blockIdx.x * 64;
  const int lane = tid & 63, w = tid >> 6;
  const int wm = w >> 1, wn = w & 1;
  const int g = lane >> 4, c = lane & 15;
  f32x4 acc[4][2];
  #pragma unroll
  for (int i = 0; i < 4; i++)
    #pragma unroll
    for (int j = 0; j < 2; j++) acc[i][j] = f32x4{0,0,0,0};

  for (int k0 = 0; k0 < K; k0 += 32){
    __syncthreads();
    #pragma unroll
    for (int i = 0; i < 2; i++){
      int ch = tid + i * 256;
      int row = ch >> 2, c4 = ch & 3;
      *(uint4*)&lA[0][row][c4*8] = *(const uint4*)&Ahi[(size_t)(m0+row)*K + k0 + c4*8];
      *(uint4*)&lA[1][row][c4*8] = *(const uint4*)&Alo[(size_t)(m0+row)*K + k0 + c4*8];
    }
    { int row = tid >> 2, c4 = tid & 3;
      *(uint4*)&lB[0][row][c4*8] = *(const uint4*)&Bhi[(size_t)(n0+row)*K + k0 + c4*8];
      *(uint4*)&lB[1][row][c4*8] = *(const uint4*)&Blo[(size_t)(n0+row)*K + k0 + c4*8];
    }
    __syncthreads();
    s16x8 ah[4], al[4], bh[2], bl[2];
    #pragma unroll
    for (int mf = 0; mf < 4; mf++){
      ah[mf] = *(const s16x8*)&lA[0][wm*64 + mf*16 + c][g*8];
      al[mf] = *(const s16x8*)&lA[1][wm*64 + mf*16 + c][g*8];
    }
    #pragma unroll
    for (int nf = 0; nf < 2; nf++){
      bh[nf] = *(const s16x8*)&lB[0][wn*32 + nf*16 + c][g*8];
      bl[nf] = *(const s16x8*)&lB[1][wn*32 + nf*16 + c][g*8];
    }
    #pragma unroll
    for (int mf = 0; mf < 4; mf++)
      #pragma unroll
      for (int nf = 0; nf < 2; nf++){
        acc[mf][nf] = __builtin_amdgcn_mfma_f32_16x16x32_bf16(ah[mf], bh[nf], acc[mf][nf], 0,0,0);
        acc[mf][nf] = __builtin_amdgcn_mfma_f32_16x16x32_bf16(ah[mf], bl[nf], acc[mf][nf], 0,0,0);
        acc[mf][nf] = __builtin_amdgcn_mfma_f32_16x16x32_bf16(al[mf], bh[nf], acc[mf][nf], 0,0,0);
      }
  }
  #pragma unroll
  for (int mf = 0; mf < 4; mf++)
    #pragma unroll
    for (int nf = 0; nf < 2; nf++)
      #pragma unroll
      for (int r = 0; r < 4; r++){
        int m = m0 + wm*64 + mf*16 + g*4 + r;
        int n = n0 + wn*32 + nf*16 + c;
        float v = acc[mf][nf][r];
        if (OMODE == 2){
          ((float*)out0)[(size_t)m * 1024 + n] = v;
        } else {
          int b = m >> 11, s = m & 2047, h = n >> 6, d = n & 63;
          if (OMODE == 0){
            size_t idx = (((size_t)(b*16 + h)) * 2048 + s) * 64 + d;
            u16 hv = f2bf(v);
            ((u16*)out0)[idx] = hv;
            ((u16*)out1)[idx] = f2bf(v - bf2f(hv));
          } else {
            size_t idx = (((size_t)(b*16 + h)) * 64 + d) * 2048 + s;
            ((u16*)out0)[idx] = f2bf(v);
          }
        }
      }
}

// ---------------- fused QK^T pass: MODE 0 coarse hist, 1 fine hist, 2 attention ---
template<int MODE>
__global__ __launch_bounds__(256) void attn_k(
    const u16* __restrict__ qhi, const u16* __restrict__ qlo,
    const u16* __restrict__ khi, const u16* __restrict__ klo,
    const u16* __restrict__ vt,
    u16* __restrict__ ohi, u16* __restrict__ olo,
    unsigned* __restrict__ ghist, const float* __restrict__ sc)
{
  extern __shared__ char smem[];
  u16* lKh = (u16*)smem;                    // [64][72]
  u16* lKl = (u16*)(smem + 9216);           // [64][72]
  u16* lV  = (u16*)(smem + 18432);          // [64][72]        (MODE 2)
  u16* lP  = (u16*)(smem + 27648);          // [4][32][72]     (MODE 2)
  unsigned* lh = (unsigned*)(smem + 18432); // [8192]          (MODE 0/1)

  const int tid = threadIdx.x, lane = tid & 63, w = tid >> 6;
  const int g = lane >> 4, c = lane & 15;
  const int bh = blockIdx.x >> 4, qt = blockIdx.x & 15;
  const int qrow0 = qt * 128 + w * 32;
  const size_t base = (size_t)bh * (2048 * 64);

  if (MODE != 2){
    #pragma unroll
    for (int i = 0; i < 32; i++) lh[tid + i*256] = 0u;
  }
  float rlo = 0.f, thr = 0.f;
  if (MODE == 1) rlo = sc[0];
  if (MODE == 2) thr = sc[1];

  s16x8 qfh[2][2], qfl[2][2];
  #pragma unroll
  for (int mf = 0; mf < 2; mf++)
    #pragma unroll
    for (int ks = 0; ks < 2; ks++){
      size_t off = base + (size_t)(qrow0 + mf*16 + c) * 64 + ks*32 + g*8;
      qfh[mf][ks] = *(const s16x8*)&qhi[off];
      qfl[mf][ks] = *(const s16x8*)&qlo[off];
    }

  f32x4 O[2][4];
  float mrun[2][4], zrun[2][4];
  if (MODE == 2){
    #pragma unroll
    for (int mf = 0; mf < 2; mf++)
      #pragma unroll
      for (int j = 0; j < 4; j++){ O[mf][j] = f32x4{0,0,0,0}; mrun[mf][j] = -1e30f; zrun[mf][j] = 0.f; }
  }

  for (int kt = 0; kt < 32; kt++){
    __syncthreads();
    #pragma unroll
    for (int i = 0; i < 2; i++){
      int ch = tid + i * 256;
      int row = ch >> 3, c8 = ch & 7;
      size_t go = base + (size_t)(kt*64 + row) * 64 + c8*8;
      *(uint4*)&lKh[row*72 + c8*8] = *(const uint4*)&khi[go];
      *(uint4*)&lKl[row*72 + c8*8] = *(const uint4*)&klo[go];
    }
    if (MODE == 2){
      #pragma unroll
      for (int i = 0; i < 2; i++){
        int ch = tid + i * 256;
        int row = ch >> 3, c8 = ch & 7;
        size_t go = base + (size_t)row * 2048 + kt*64 + c8*8;
        *(uint4*)&lV[row*72 + c8*8] = *(const uint4*)&vt[go];
      }
    }
    __syncthreads();

    s16x8 kfh[4][2], kfl[4][2];
    #pragma unroll
    for (int nf = 0; nf < 4; nf++)
      #pragma unroll
      for (int ks = 0; ks < 2; ks++){
        int off = (nf*16 + c) * 72 + ks*32 + g*8;
        kfh[nf][ks] = *(const s16x8*)&lKh[off];
        kfl[nf][ks] = *(const s16x8*)&lKl[off];
      }

    f32x4 sa[2][4];
    #pragma unroll
    for (int mf = 0; mf < 2; mf++)
      #pragma unroll
      for (int nf = 0; nf < 4; nf++){
        f32x4 a = f32x4{0,0,0,0};
        #pragma unroll
        for (int ks = 0; ks < 2; ks++){
          a = __builtin_amdgcn_mfma_f32_16x16x32_bf16(qfh[mf][ks], kfh[nf][ks], a, 0,0,0);
          a = __builtin_amdgcn_mfma_f32_16x16x32_bf16(qfh[mf][ks], kfl[nf][ks], a, 0,0,0);
          a = __builtin_amdgcn_mfma_f32_16x16x32_bf16(qfl[mf][ks], kfh[nf][ks], a, 0,0,0);
        }
        sa[mf][nf] = a * 0.125f;
      }

    if (MODE != 2){
      #pragma unroll
      for (int mf = 0; mf < 2; mf++)
        #pragma unroll
        for (int nf = 0; nf < 4; nf++)
          #pragma unroll
          for (int r = 0; r < 4; r++){
            float a = __builtin_fabsf(sa[mf][nf][r]);
            if (MODE == 0){
              int idx = (int)fminf(a * 512.f, 8191.f);
              atomicAdd(&lh[idx], 1u);
            } else {
              float t = (a - rlo) * 4194304.f;  // 512*8192
              if (t >= 0.f && t < 8192.f) atomicAdd(&lh[(int)t], 1u);
            }
          }
    } else {
      #pragma unroll
      for (int mf = 0; mf < 2; mf++)
        #pragma unroll
        for (int r = 0; r < 4; r++){
          float tm = -1e30f;
          #pragma unroll
          for (int nf = 0; nf < 4; nf++){
            float v = sa[mf][nf][r];
            if (__builtin_fabsf(v) >= thr) tm = fmaxf(tm, v);
          }
          tm = fmaxf(tm, __shfl_xor(tm, 1, 64));
          tm = fmaxf(tm, __shfl_xor(tm, 2, 64));
          tm = fmaxf(tm, __shfl_xor(tm, 4, 64));
          tm = fmaxf(tm, __shfl_xor(tm, 8, 64));
          float mnew = fmaxf(mrun[mf][r], tm);
          float alpha = __expf(mrun[mf][r] - mnew);
          mrun[mf][r] = mnew;
          float ps = 0.f;
          #pragma unroll
          for (int nf = 0; nf < 4; nf++){
            float v = sa[mf][nf][r];
            float pv = (__builtin_fabsf(v) >= thr) ? __expf(v - mnew) : 0.f;
            ps += pv;
            lP[w*2304 + (mf*16 + g*4 + r)*72 + nf*16 + c] = f2bf(pv);
          }
          ps += __shfl_xor(ps, 1, 64);
          ps += __shfl_xor(ps, 2, 64);
          ps += __shfl_xor(ps, 4, 64);
          ps += __shfl_xor(ps, 8, 64);
          zrun[mf][r] = zrun[mf][r] * alpha + ps;
          #pragma unroll
          for (int j = 0; j < 4; j++) O[mf][j][r] *= alpha;
        }
      __syncthreads();  // P visible to whole wave/block before PV reads
      s16x8 pa[2][2], vb[4][2];
      #pragma unroll
      for (int mf = 0; mf < 2; mf++)
        #pragma unroll
        for (int ks = 0; ks < 2; ks++)
          pa[mf][ks] = *(const s16x8*)&lP[w*2304 + (mf*16 + c)*72 + ks*32 + g*8];
      #pragma unroll
      for (int nf = 0; nf < 4; nf++)
        #pragma unroll
        for (int ks = 0; ks < 2; ks++)
          vb[nf][ks] = *(const s16x8*)&lV[(nf*16 + c)*72 + ks*32 + g*8];
      #pragma unroll
      for (int mf = 0; mf < 2; mf++)
        #pragma unroll
        for (int nf = 0; nf < 4; nf++)
          #pragma unroll
          for (int ks = 0; ks < 2; ks++)
            O[mf][nf] = __builtin_amdgcn_mfma_f32_16x16x32_bf16(pa[mf][ks], vb[nf][ks], O[mf][nf], 0,0,0);
    }
  }

  if (MODE != 2){
    __syncthreads();
    #pragma unroll
    for (int i = 0; i < 32; i++){
      unsigned cnt = lh[tid + i*256];
      if (cnt) atomicAdd(&ghist[tid + i*256], cnt);
    }
  } else {
    const int b = bh >> 4, h = bh & 15;
    #pragma unroll
    for (int mf = 0; mf < 2; mf++)
      #pragma unroll
      for (int r = 0; r < 4; r++){
        float z = zrun[mf][r];
        float inv = (z > 0.f) ? (1.0f / z) : 0.f;
        int srow = qrow0 + mf*16 + g*4 + r;
        #pragma unroll
        for (int nf = 0; nf < 4; nf++){
          float v = O[mf][nf][r] * inv;
          int d = nf*16 + c;
          size_t idx = ((size_t)(b*2048 + srow)) * 1024 + h*64 + d;
          u16 hv = f2bf(v);
          ohi[idx] = hv;
          olo[idx] = f2bf(v - bf2f(hv));
        }
      }
  }
}

// ---------------- quantile scans ----------------
__global__ __launch_bounds__(256) void scan_coarse(const unsigned* __restrict__ hist,
    float* __restrict__ sc, unsigned* __restrict__ basec){
  __shared__ unsigned part[256];
  __shared__ unsigned bins[8192];
  int tid = threadIdx.x;
  unsigned s = 0;
  for (int i = 0; i < 32; i++){ unsigned v = hist[tid*32 + i]; bins[tid*32 + i] = v; s += v; }
  part[tid] = s;
  __syncthreads();
  if (tid == 0){
    unsigned cum = 0; int seg = 0;
    for (; seg < 256; seg++){ if (cum + part[seg] > RANK) break; cum += part[seg]; }
    int b = seg * 32;
    while (cum + bins[b] <= RANK){ cum += bins[b]; b++; }
    sc[0] = (float)b * CW;
    basec[0] = cum;
  }
}

__global__ __launch_bounds__(256) void scan_fine(const unsigned* __restrict__ hist,
    float* __restrict__ sc, const unsigned* __restrict__ basec){
  __shared__ unsigned part[256];
  __shared__ unsigned bins[8192];
  int tid = threadIdx.x;
  unsigned s = 0;
  for (int i = 0; i < 32; i++){ unsigned v = hist[tid*32 + i]; bins[tid*32 + i] = v; s += v; }
  part[tid] = s;
  __syncthreads();
  if (tid == 0){
    const float fw = CW / 8192.0f;
    unsigned rank2 = RANK - basec[0];
    unsigned cum = 0; int seg = 0; bool ok = false;
    for (; seg < 256; seg++){ if (cum + part[seg] > rank2){ ok = true; break; } cum += part[seg]; }
    float thr;
    if (!ok){
      thr = sc[0] + CW;
    } else {
      int b = seg * 32;
      while (cum + bins[b] <= rank2){ cum += bins[b]; b++; }
      unsigned cnt = bins[b];
      float frac = ((float)(rank2 - cum) + 0.5f + QFRAC) / (float)cnt;
      if (frac > 1.f) frac = 1.f;
      thr = sc[0] + ((float)b + frac) * fw;
    }
    sc[1] = thr;
  }
}

// ---------------- host ----------------
extern "C" void kernel_launch(void* const* d_in, const int* in_sizes, int n_in,
                              void* d_out, int out_size, void* d_ws, size_t ws_size,
                              hipStream_t stream)
{
  const float* x  = (const float*)d_in[0];
  const float* Wq = (const float*)d_in[1];
  const float* Wk = (const float*)d_in[2];
  const float* Wv = (const float*)d_in[3];
  const float* Wo = (const float*)d_in[4];

  char* p = (char*)d_ws;
  auto alloc = [&](size_t bytes) -> char* {
    char* r = p; p += (bytes + 255) & ~(size_t)255; return r;
  };
  const size_t NX = 4194304, NW = 1048576;
  u16* xh  = (u16*)alloc(NX*2); u16* xl  = (u16*)alloc(NX*2);
  u16* wqh = (u16*)alloc(NW*2); u16* wql = (u16*)alloc(NW*2);
  u16* wkh = (u16*)alloc(NW*2); u16* wkl = (u16*)alloc(NW*2);
  u16* wvh = (u16*)alloc(NW*2); u16* wvl = (u16*)alloc(NW*2);
  u16* woh = (u16*)alloc(NW*2); u16* wol = (u16*)alloc(NW*2);
  u16* qh  = (u16*)alloc(NX*2); u16* ql  = (u16*)alloc(NX*2);
  u16* kh  = (u16*)alloc(NX*2); u16* kl  = (u16*)alloc(NX*2);
  u16* vth = (u16*)alloc(NX*2);
  u16* oh  = (u16*)alloc(NX*2); u16* ol  = (u16*)alloc(NX*2);
  unsigned* histc = (unsigned*)alloc(8192*4);
  unsigned* histf = (unsigned*)alloc(8192*4);
  float*    sc    = (float*)alloc(256);
  unsigned* basec = (unsigned*)alloc(256);
  if ((size_t)(p - (char*)d_ws) > ws_size) return;  // insufficient workspace

  hipMemsetAsync(histc, 0, 8192*4*2, stream);

  split_k<<<dim3(512), dim3(256), 0, stream>>>(x,  xh,  xl,  (int)(NX/4));
  split_k<<<dim3(128), dim3(256), 0, stream>>>(Wq, wqh, wql, (int)(NW/4));
  split_k<<<dim3(128), dim3(256), 0, stream>>>(Wk, wkh, wkl, (int)(NW/4));
  split_k<<<dim3(128), dim3(256), 0, stream>>>(Wv, wvh, wvl, (int)(NW/4));
  split_k<<<dim3(128), dim3(256), 0, stream>>>(Wo, woh, wol, (int)(NW/4));

  dim3 gg(16, 32), gb(256);
  gemm_bt<0><<<gg, gb, 0, stream>>>(xh, xl, wqh, wql, (void*)qh, (void*)ql, 1024);
  gemm_bt<0><<<gg, gb, 0, stream>>>(xh, xl, wkh, wkl, (void*)kh, (void*)kl, 1024);
  gemm_bt<1><<<gg, gb, 0, stream>>>(xh, xl, wvh, wvl, (void*)vth, nullptr, 1024);

  attn_k<0><<<dim3(512), gb, 51200, stream>>>(qh, ql, kh, kl, nullptr, nullptr, nullptr, histc, sc);
  scan_coarse<<<dim3(1), gb, 0, stream>>>(histc, sc, basec);
  attn_k<1><<<dim3(512), gb, 51200, stream>>>(qh, ql, kh, kl, nullptr, nullptr, nullptr, histf, sc);
  scan_fine<<<dim3(1), gb, 0, stream>>>(histf, sc, basec);
  attn_k<2><<<dim3(512), gb, 46080, stream>>>(qh, ql, kh, kl, vth, oh, ol, nullptr, sc);

  gemm_bt<2><<<gg, gb, 0, stream>>>(oh, ol, woh, wol, d_out, nullptr, 1024);
}